// Round 19
// baseline (16.969 us; speedup 1.0000x reference)
//
#include <hip/hip_runtime.h>

namespace {

typedef float v2f __attribute__((ext_vector_type(2)));

constexpr int kT   = 8;    // timesteps
constexpr int kB   = 256;  // batch
constexpr int kNQ  = 8;    // qubits per circuit
constexpr int kNB  = 8;    // blocks
constexpr int kD   = 64;   // features
constexpr int kNL  = 2;    // quantum layers
constexpr int kGateF = 8;
constexpr int kCircStride = 16 * kGateF + 4;   // 132: pad so u-strides hit distinct banks

// Walsh parity masks (validated r4-r18): wire-set of output w, bit j = wire j.
constexpr unsigned long long kMaskPacked =
    (0x54ULL << 0) | (0xA8ULL << 8) | (0x05ULL << 16) | (0x0AULL << 24) |
    (0x15ULL << 32) | (0x2AULL << 40) | (0x55ULL << 48) | (0xAAULL << 56);

__device__ __forceinline__ v2f mk(float a, float b) { v2f r; r.x = a; r.y = b; return r; }

// ---------------- fast sincos of a/2 ----------------
__device__ __forceinline__ void fastsc(float a, float& s, float& c) {
#if __has_builtin(__builtin_amdgcn_sinf) && __has_builtin(__builtin_amdgcn_cosf)
    const float r = a * 0.07957747154594767f;   // 0.5 / (2*pi)
    s = __builtin_amdgcn_sinf(r);
    c = __builtin_amdgcn_cosf(r);
#else
    __sincosf(0.5f * a, &s, &c);
#endif
}

// B_j entry select: h_j if wire j in mask, else identity.
__device__ __forceinline__ void bsel(const float* __restrict__ hh, int j, unsigned mask,
                                     float& b00, float& b01r, float& b01i, float& b11) {
    const float* hp = hh + j * kGateF;
    const bool m = (mask >> j) & 1u;
    const float a = hp[0], hr = hp[1], hi = hp[2];
    b00  = m ? a   : 1.0f;
    b01r = m ? hr  : 0.0f;
    b01i = m ? hi  : 0.0f;
    b11  = m ? -a  : 1.0f;
}

// ---------------- ONE packed chain of the 16-state transfer-matrix DP --------------
// E_w = sum over (b0,b'0) slices; CHAIN 0 packs slices {(0,0),(1,1)}, CHAIN 1 packs
// {(0,1),(1,0)}. j=2..7 recurrence is slice-independent (scalar coeffs x v2f).
// [DP validated r15/r16; packing validated r18 — this splits r18's two chains
//  across waves instead of registers]
template <int CHAIN>
__device__ __forceinline__ float simdp_chain(const float (&ang)[8],
                                             const float* __restrict__ g0,  // d0 (LDS)
                                             const float* __restrict__ hh,  // d1 (LDS)
                                             unsigned mask) {
    // per-wire density-matrix entries: rho = sigma sigma^dag
    float r00[8], r11[8], r01r[8], r01i[8];
#pragma unroll
    for (int j = 0; j < 8; ++j) {
        float sn, cs;
        fastsc(ang[j], sn, cs);
        const float* gp = g0 + j * kGateF;
        const float s0r = gp[0] * cs + gp[2] * sn, s0i = gp[1] * cs + gp[3] * sn;
        const float s1r = gp[4] * cs + gp[6] * sn, s1i = gp[5] * cs + gp[7] * sn;
        r00[j]  = s0r * s0r + s0i * s0i;
        r11[j]  = s1r * s1r + s1i * s1i;
        r01r[j] = s0r * s1r + s0i * s1i;   // sigma0 * conj(sigma1)
        r01i[j] = s0i * s1r - s0r * s1i;
    }

    v2f Vr[2][2], Vi[2][2];

    // ---- init fused with step j=1: V = rho0[b0,b'0] * rho1[p^b0, p'^b'0] * B1[p'][p]
    {
        float b00, b01r, b01i, b11;
        bsel(hh, 1, mask, b00, b01r, b01i, b11);
#pragma unroll
        for (int p = 0; p < 2; ++p)
#pragma unroll
        for (int pp = 0; pp < 2; ++pp) {
            float B1r, B1i;
            if (p == pp) { B1r = p ? b11 : b00; B1i = 0.0f; }
            else if (pp == 0) { B1r = b01r; B1i = b01i; }
            else { B1r = b01r; B1i = -b01i; }
            v2f m1r, m1i;
            if constexpr (CHAIN == 0) {
                // q0 = {rho0[0,0], rho0[1,1]} (real); m1 = {rho1[p][pp], rho1[p^1][pp^1]}
                const v2f q0r = mk(r00[0], r11[0]);
                if (p == pp) {
                    m1r = p ? mk(r11[1], r00[1]) : mk(r00[1], r11[1]);
                    m1i = mk(0.0f, 0.0f);
                } else if (p == 0) { m1r = mk(r01r[1], r01r[1]); m1i = mk(r01i[1], -r01i[1]); }
                else               { m1r = mk(r01r[1], r01r[1]); m1i = mk(-r01i[1], r01i[1]); }
                const v2f tr = q0r * m1r;
                const v2f ti = q0r * m1i;
                Vr[p][pp] = tr * B1r - ti * B1i;
                Vi[p][pp] = tr * B1i + ti * B1r;
            } else {
                // q0 = {rho0[0,1], rho0[1,0]}; m1 = {rho1[p][pp^1], rho1[p^1][pp]}
                const v2f q0r = mk(r01r[0], r01r[0]);
                const v2f q0i = mk(r01i[0], -r01i[0]);
                if (p != pp) {
                    m1r = (p == 0) ? mk(r00[1], r11[1]) : mk(r11[1], r00[1]);
                    m1i = mk(0.0f, 0.0f);
                } else if (p == 0) { m1r = mk(r01r[1], r01r[1]); m1i = mk(r01i[1], -r01i[1]); }
                else               { m1r = mk(r01r[1], r01r[1]); m1i = mk(-r01i[1], r01i[1]); }
                const v2f tr = q0r * m1r - q0i * m1i;
                const v2f ti = q0r * m1i + q0i * m1r;
                Vr[p][pp] = tr * B1r - ti * B1i;
                Vi[p][pp] = tr * B1i + ti * B1r;
            }
        }
    }

    // ---- steps j = 2..7: V'[p,p'] = B_j[p'][p] * sum_{q,q'} rho_j[p^q,p'^q'] V[q,q']
#pragma unroll
    for (int j = 2; j < 8; ++j) {
        float b00, b01r, b01i, b11;
        bsel(hh, j, mask, b00, b01r, b01i, b11);
        const float c00 = r00[j], c11 = r11[j], c01r = r01r[j], c01i = r01i[j];
        v2f nr[2][2], ni[2][2];
#pragma unroll
        for (int p = 0; p < 2; ++p)
#pragma unroll
        for (int pp = 0; pp < 2; ++pp) {
            v2f sr = c00 * Vr[p][pp] + c11 * Vr[p ^ 1][pp ^ 1];
            v2f si = c00 * Vi[p][pp] + c11 * Vi[p ^ 1][pp ^ 1];
            sr += c01r * Vr[p][pp ^ 1] - c01i * Vi[p][pp ^ 1];
            si += c01r * Vi[p][pp ^ 1] + c01i * Vr[p][pp ^ 1];
            sr += c01r * Vr[p ^ 1][pp] + c01i * Vi[p ^ 1][pp];
            si += c01r * Vi[p ^ 1][pp] - c01i * Vr[p ^ 1][pp];
            float Br, Bi;
            if (p == pp) { Br = p ? b11 : b00; Bi = 0.0f; }
            else if (pp == 0) { Br = b01r; Bi = b01i; }
            else { Br = b01r; Bi = -b01i; }
            nr[p][pp] = sr * Br - si * Bi;
            ni[p][pp] = sr * Bi + si * Br;
        }
        Vr[0][0] = nr[0][0]; Vi[0][0] = ni[0][0];
        Vr[0][1] = nr[0][1]; Vi[0][1] = ni[0][1];
        Vr[1][0] = nr[1][0]; Vi[1][0] = ni[1][0];
        Vr[1][1] = nr[1][1]; Vi[1][1] = ni[1][1];
    }

    // ---- final l_0 wrap: E = Re sum V[p][p'] * B0[p'^b'0][p^b0], packed per slice ----
    v2f acc = mk(0.0f, 0.0f);
    {
        float b00, b01r, b01i, b11;
        bsel(hh, 0, mask, b00, b01r, b01i, b11);
#pragma unroll
        for (int p = 0; p < 2; ++p)
#pragma unroll
        for (int pp = 0; pp < 2; ++pp) {
            v2f Br, Bi;
            if constexpr (CHAIN == 0) {
                // B = {B0[pp][p], B0[pp^1][p^1]}
                if (p == pp) { Br = p ? mk(b11, b00) : mk(b00, b11); Bi = mk(0.0f, 0.0f); }
                else if (p == 0) { Br = mk(b01r, b01r); Bi = mk(-b01i, b01i); }
                else             { Br = mk(b01r, b01r); Bi = mk(b01i, -b01i); }
            } else {
                // B = {B0[pp^1][p], B0[pp][p^1]}
                if (p != pp) { Br = (p == 0) ? mk(b00, b11) : mk(b11, b00); Bi = mk(0.0f, 0.0f); }
                else if (p == 0) { Br = mk(b01r, b01r); Bi = mk(-b01i, b01i); }
                else             { Br = mk(b01r, b01r); Bi = mk(b01i, -b01i); }
            }
            acc += Vr[p][pp] * Br - Vi[p][pp] * Bi;
        }
    }
    return acc.x + acc.y;
}

// ---------------- single fused kernel ----------------
// block = 256 threads = 2 (t,b) tiles x 2 chain-waves. Gate build into LDS (one
// slot/thread, tt block-uniform). Each wave runs ONE packed chain; chains meet
// through part[] at the layer boundary and at the end.
__global__ __launch_bounds__(256) void fused_kernel(const float* __restrict__ x,
                                                    const float* __restrict__ theta,
                                                    float* __restrict__ out) {
    __shared__ float gl[kNL * kNB * kCircStride];   // 2112 floats = 8448 B
    __shared__ float part[2][2][64];                // [tile][chain][lane]

    const int tid  = threadIdx.x;
    const int wave = tid >> 6;
    const int s    = wave >> 1;       // tile within block
    const int c    = wave & 1;        // chain
    const int lane = tid & 63;
    const int wt = blockIdx.x * 2 + s;   // global tile id
    const int tt = wt >> 8;              // timestep (block-uniform: 2|256)
    const int b  = wt & 255;             // sample
    const int u  = lane >> 3;            // circuit within timestep
    const int w  = lane & 7;             // output wire
    const unsigned mask = (unsigned)((kMaskPacked >> (w * 8)) & 0xFF);

    // ---- gate build: one slot per thread (coalesced theta reads) ----
    {
        const int l  = tid >> 7;
        const int uu = (tid >> 4) & 7;
        const int g  = tid & 15;         // d*8 + wire
        const int d  = g >> 3, ww = g & 7;
        const float* th = theta + ((((tt * kNL + l) * kNB + uu) * 2 + d) * kNQ + ww) * 3;
        const float phi = th[0], tht = th[1], omg = th[2];
        float st, ct, sp, cp, sm, cm;
        fastsc(tht, st, ct);
        fastsc(phi + omg, sp, cp);
        fastsc(phi - omg, sm, cm);
        const float u00r =  ct * cp, u00i = -ct * sp;
        const float u01r = -st * cm, u01i = -st * sm;
        const float u10r =  st * cm, u10i = -st * sm;
        const float u11r =  ct * cp, u11i =  ct * sp;
        float* o = &gl[(l * kNB + uu) * kCircStride + g * kGateF];
        if (d == 1) {
            // h = g^dag Z g (Hermitian, traceless)
            o[0] = (u00r * u00r + u00i * u00i) - (u10r * u10r + u10i * u10i);
            o[1] = (u00r * u01r + u00i * u01i) - (u10r * u11r + u10i * u11i);
            o[2] = (u00r * u01i - u00i * u01r) - (u10r * u11i - u10i * u11r);
        } else {
            o[0] = u00r;  o[1] = u00i;
            o[2] = u01r;  o[3] = u01i;
            o[4] = u10r;  o[5] = u10i;
            o[6] = u11r;  o[7] = u11i;
        }
    }
    __syncthreads();

    // ---- phase 0: layer-0 circuit (t,u) ----
    float ang[8];
    {
        const float* ab = x + ((b * kT + tt) * kD + u * kNQ);
#pragma unroll
        for (int j = 0; j < 8; ++j) ang[j] = ab[j];
    }
    const float* base0 = &gl[u * kCircStride];
    float E = c ? simdp_chain<1>(ang, base0, base0 + 8 * kGateF, mask)
                : simdp_chain<0>(ang, base0, base0 + 8 * kGateF, mask);
    part[s][c][lane] = E;
    __syncthreads();

    // ---- phase-1 angles: ang[i] = E(circuit i, wire u) = sum_c part[s][c][i*8+u] ----
#pragma unroll
    for (int i = 0; i < 8; ++i) {
        const int sl = i * 8 + u;
        ang[i] = part[s][0][sl] + part[s][1][sl];
    }

    // ---- phase 1: layer-1 circuit (t,u) ----
    const float* base1 = &gl[(kNB + u) * kCircStride];
    E = c ? simdp_chain<1>(ang, base1, base1 + 8 * kGateF, mask)
          : simdp_chain<0>(ang, base1, base1 + 8 * kGateF, mask);
    part[s][c][lane] = E;
    __syncthreads();

    if (c == 0) {
        out[(b * kT + tt) * kD + lane] = part[s][0][lane] + part[s][1][lane];
    }
}

}  // namespace

extern "C" void kernel_launch(void* const* d_in, const int* in_sizes, int n_in,
                              void* d_out, int out_size, void* d_ws, size_t ws_size,
                              hipStream_t stream) {
    const float* x     = (const float*)d_in[0];   // (B, T, D) fp32
    const float* theta = (const float*)d_in[1];   // (T, NL, NB, DEPTH, NQ, 3) fp32
    float* out = (float*)d_out;                   // (B, T, D) fp32

    // 1024 blocks x 4 waves = 4096 waves (16/CU): 2 tiles x 2 chain-waves per block
    fused_kernel<<<kT * kB / 2, 256, 0, stream>>>(x, theta, out);
}

// Round 20
// 11.560 us; speedup vs baseline: 1.4679x; 1.4679x over previous
//
#include <hip/hip_runtime.h>

namespace {

typedef float v2f __attribute__((ext_vector_type(2)));

constexpr int kT   = 8;    // timesteps
constexpr int kB   = 256;  // batch
constexpr int kNQ  = 8;    // qubits per circuit
constexpr int kNB  = 8;    // blocks
constexpr int kD   = 64;   // features
constexpr int kNL  = 2;    // quantum layers
constexpr int kGateF = 8;
constexpr int kCircStride = 16 * kGateF + 4;   // 132: pad so u-strides hit distinct banks

// Walsh parity masks (validated r4-r19): wire-set of output w, bit j = wire j.
constexpr unsigned long long kMaskPacked =
    (0x54ULL << 0) | (0xA8ULL << 8) | (0x05ULL << 16) | (0x0AULL << 24) |
    (0x15ULL << 32) | (0x2AULL << 40) | (0x55ULL << 48) | (0xAAULL << 56);

__device__ __forceinline__ v2f mk(float a, float b) { v2f r; r.x = a; r.y = b; return r; }
__device__ __forceinline__ v2f swp(v2f v) { return __builtin_shufflevector(v, v, 1, 0); }

// ---------------- fast sincos of a/2 ----------------
__device__ __forceinline__ void fastsc(float a, float& s, float& c) {
#if __has_builtin(__builtin_amdgcn_sinf) && __has_builtin(__builtin_amdgcn_cosf)
    const float r = a * 0.07957747154594767f;   // 0.5 / (2*pi)
    s = __builtin_amdgcn_sinf(r);
    c = __builtin_amdgcn_cosf(r);
#else
    __sincosf(0.5f * a, &s, &c);
#endif
}

// B_j entry select: h_j if wire j in mask, else identity.
__device__ __forceinline__ void bsel(const float* __restrict__ hh, int j, unsigned mask,
                                     float& b00, float& b01r, float& b01i, float& b11) {
    const float* hp = hh + j * kGateF;
    const bool m = (mask >> j) & 1u;
    const float a = hp[0], hr = hp[1], hi = hp[2];
    b00  = m ? a   : 1.0f;
    b01r = m ? hr  : 0.0f;
    b01i = m ? hi  : 0.0f;
    b11  = m ? -a  : 1.0f;
}

// ---------------- symmetry-reduced 16-state transfer-matrix DP --------------------
// Base DP validated r15/r16; v2f slice-packing validated r18. New reduction:
// V_(b0,bp)[p][pp] = conj(V_(bp,b0)[pp][p]) (rho, B Hermitian; preserved by the
// update). Chain A = slices {(0,0),(1,1)}: HERMITIAN 2x2 each -> state {D0,D1 real
// diag, O off-diag} packed over slices in v2f. Chain B = slice (0,1) only (slice
// (1,0) is its conjugate-transpose => contributes the same E): state packed as
// P=(V00,V11), Q=(V01,V10) complex v2f. Total E = E_A + 2*E_B.
__device__ __forceinline__ float simdp(const float (&ang)[8],
                                       const float* __restrict__ g0,   // d0 gates (LDS)
                                       const float* __restrict__ hh,   // d1 herms (LDS)
                                       unsigned mask) {
    // per-wire density-matrix entries: rho = sigma sigma^dag
    float r00[8], r11[8], r01r[8], r01i[8];
#pragma unroll
    for (int j = 0; j < 8; ++j) {
        float sn, cs;
        fastsc(ang[j], sn, cs);
        const float* gp = g0 + j * kGateF;
        const float s0r = gp[0] * cs + gp[2] * sn, s0i = gp[1] * cs + gp[3] * sn;
        const float s1r = gp[4] * cs + gp[6] * sn, s1i = gp[5] * cs + gp[7] * sn;
        r00[j]  = s0r * s0r + s0i * s0i;
        r11[j]  = s1r * s1r + s1i * s1i;
        r01r[j] = s0r * s1r + s0i * s1i;   // sigma0 * conj(sigma1)
        r01i[j] = s0i * s1r - s0r * s1i;
    }

    v2f D0, D1, Or_, Oi_;      // chain A (Hermitian, slices packed in v2f)
    v2f Pr, Pi, Qr, Qi;        // chain B (slice (0,1): P=(V00,V11), Q=(V01,V10))

    // ---- init fused with step j=1: V = rho0[b0,bp] * rho1[p^b0, pp^bp] * B1[pp][p]
    {
        float e00, e01r, e01i, e11;
        bsel(hh, 1, mask, e00, e01r, e01i, e11);
        const float c1r = r01r[1], c1i = r01i[1];
        // chain A
        const v2f q0 = mk(r00[0], r11[0]);
        const v2f m  = mk(r00[1], r11[1]);
        D0 = q0 * m * e00;
        D1 = q0 * swp(m) * e11;
        const v2f Orp = q0 * c1r;                 // pre-B off-diag (r00*c1, r11*conj(c1))
        const v2f Oip = q0 * mk(c1i, -c1i);
        Or_ = e01r * Orp + e01i * Oip;            // * conj(B1_01)
        Oi_ = e01r * Oip - e01i * Orp;
        // chain B (z = rho0[0][1])
        const float zr = r01r[0], zi = r01i[0];
        const float w1r = zr * c1r - zi * c1i, w1i = zr * c1i + zi * c1r;   // z*c1
        const float w2r = zr * c1r + zi * c1i, w2i = zi * c1r - zr * c1i;   // z*conj(c1)
        Pr = mk(w1r * e00, w2r * e11);
        Pi = mk(w1i * e00, w2i * e11);
        const float ur = zr * r00[1], ui = zi * r00[1];   // z*r00'
        const float vr = zr * r11[1], vi = zi * r11[1];   // z*r11'
        Qr = mk(ur * e01r + ui * e01i, vr * e01r - vi * e01i);   // u*conj(B01), v*B01
        Qi = mk(ui * e01r - ur * e01i, vi * e01r + vr * e01i);
    }

    // ---- steps j = 2..7 ----
#pragma unroll
    for (int j = 2; j < 8; ++j) {
        float e00, e01r, e01i, e11;
        bsel(hh, j, mask, e00, e01r, e01i, e11);
        const float c00 = r00[j], c11 = r11[j], c01r = r01r[j], c01i = r01i[j];
        // chain A (Hermitian update)
        {
            const v2f Ta = c01r * Or_, Tb = c01i * Oi_;
            const v2f T1 = Ta - Tb, T2 = Ta + Tb;
            const v2f S00 = c00 * D0 + c11 * D1 + 2.0f * T1;
            const v2f S11 = c00 * D1 + c11 * D0 + 2.0f * T2;
            const float cps = c00 + c11, cms = c00 - c11;
            const v2f Dp = D0 + D1, Dm = D0 - D1;
            const v2f S01r = cps * Or_ + c01r * Dp;
            const v2f S01i = cms * Oi_ + c01i * Dm;
            D0 = e00 * S00;
            D1 = e11 * S11;
            Or_ = e01r * S01r + e01i * S01i;      // * conj(B01)
            Oi_ = e01r * S01i - e01i * S01r;
        }
        // chain B (general complex update; swaps are free op_sel)
        {
            const v2f Prs = swp(Pr), Pis = swp(Pi), Qrs = swp(Qr), Qis = swp(Qi);
            const v2f SPr = c00 * Pr + c11 * Prs + c01r * (Qr + Qrs) + c01i * (Qis - Qi);
            const v2f SPi = c00 * Pi + c11 * Pis + c01r * (Qi + Qis) + c01i * (Qr - Qrs);
            const v2f SQr = c00 * Qr + c11 * Qrs + c01r * (Pr + Prs) + c01i * (Pis - Pi);
            const v2f SQi = c00 * Qi + c11 * Qis + c01r * (Pi + Pis) + c01i * (Pr - Prs);
            const v2f Bd = mk(e00, e11);
            const v2f be = mk(e01i, -e01i);
            Pr = Bd * SPr;
            Pi = Bd * SPi;
            Qr = e01r * SQr + be * SQi;           // lane x: conj(B01), lane y: B01
            Qi = e01r * SQi - be * SQr;
        }
    }

    // ---- final l_0 wrap: E = E_A + 2*E_B ----
    float e00, e01r, e01i, e11;
    bsel(hh, 0, mask, e00, e01r, e01i, e11);
    const float EA = D0.x * e00 + D0.y * e11 + D1.x * e11 + D1.y * e00
                   + 2.0f * (e01r * (Or_.x + Or_.y) + e01i * (Oi_.x - Oi_.y));
    const float EB = e01r * Pr.x + e01i * Pi.x + e01r * Pr.y - e01i * Pi.y
                   + e00 * Qr.x + e11 * Qr.y;
    return EA + 2.0f * EB;
}

// ---------------- single fused kernel: gate build (LDS) + both layers ----------------
// block = 256 threads = 4 waves, all sharing one timestep tt (256 wids/tt).
// wave = (t, sample b); lane = (u:3, w:3) computes expval w of circuit u.
__global__ __launch_bounds__(256) void fused_kernel(const float* __restrict__ x,
                                                    const float* __restrict__ theta,
                                                    float* __restrict__ out) {
    __shared__ float gl[kNL * kNB * kCircStride];   // 2112 floats = 8448 B

    const int tid  = threadIdx.x;
    const int wid  = blockIdx.x * 4 + (tid >> 6);
    const int lane = tid & 63;
    const int tt = wid >> 8;          // timestep (block-uniform)
    const int b  = wid & 255;         // sample
    const int u  = lane >> 3;         // circuit within timestep
    const int w  = lane & 7;          // output wire
    const unsigned mask = (unsigned)((kMaskPacked >> (w * 8)) & 0xFF);

    // ---- gate build: one slot per thread (coalesced theta reads) ----
    {
        const int l  = tid >> 7;
        const int uu = (tid >> 4) & 7;
        const int g  = tid & 15;         // d*8 + wire
        const int d  = g >> 3, ww = g & 7;
        const float* th = theta + ((((tt * kNL + l) * kNB + uu) * 2 + d) * kNQ + ww) * 3;
        const float phi = th[0], tht = th[1], omg = th[2];
        float st, ct, sp, cp, sm, cm;
        fastsc(tht, st, ct);
        fastsc(phi + omg, sp, cp);
        fastsc(phi - omg, sm, cm);
        const float u00r =  ct * cp, u00i = -ct * sp;
        const float u01r = -st * cm, u01i = -st * sm;
        const float u10r =  st * cm, u10i = -st * sm;
        const float u11r =  ct * cp, u11i =  ct * sp;
        float* o = &gl[(l * kNB + uu) * kCircStride + g * kGateF];
        if (d == 1) {
            // h = g^dag Z g (Hermitian, traceless)
            o[0] = (u00r * u00r + u00i * u00i) - (u10r * u10r + u10i * u10i);
            o[1] = (u00r * u01r + u00i * u01i) - (u10r * u11r + u10i * u11i);
            o[2] = (u00r * u01i - u00i * u01r) - (u10r * u11i - u10i * u11r);
        } else {
            o[0] = u00r;  o[1] = u00i;
            o[2] = u01r;  o[3] = u01i;
            o[4] = u10r;  o[5] = u10i;
            o[6] = u11r;  o[7] = u11i;
        }
    }
    __syncthreads();

    // ---- phase 0: layer-0 circuit (t,u), angles from x ----
    float ang[8];
    {
        const float* ab = x + ((b * kT + tt) * kD + u * kNQ);
#pragma unroll
        for (int j = 0; j < 8; ++j) ang[j] = ab[j];
    }
    const float* base0 = &gl[u * kCircStride];
    float E = simdp(ang, base0, base0 + 8 * kGateF, mask);

    // ---- redistribute: layer-1 circuit u needs H0[t,b,i*8+u] = lane i*8+u ----
#pragma unroll
    for (int i = 0; i < 8; ++i) ang[i] = __shfl(E, i * 8 + u, 64);

    // ---- phase 1: layer-1 circuit (t,u) ----
    const float* base1 = &gl[(kNB + u) * kCircStride];
    E = simdp(ang, base1, base1 + 8 * kGateF, mask);

    out[(b * kT + tt) * kD + u * kNQ + w] = E;   // coalesced: 64 consecutive floats/wave
}

}  // namespace

extern "C" void kernel_launch(void* const* d_in, const int* in_sizes, int n_in,
                              void* d_out, int out_size, void* d_ws, size_t ws_size,
                              hipStream_t stream) {
    const float* x     = (const float*)d_in[0];   // (B, T, D) fp32
    const float* theta = (const float*)d_in[1];   // (T, NL, NB, DEPTH, NQ, 3) fp32
    float* out = (float*)d_out;                   // (B, T, D) fp32

    // single kernel: 8 timesteps x 256 samples = 2048 waves; 4 waves/block
    fused_kernel<<<kT * kB / 4, 256, 0, stream>>>(x, theta, out);
}